// Round 1
// baseline (8806.075 us; speedup 1.0000x reference)
//
#include <hip/hip_runtime.h>

#define N_NODES  200000
#define N_EDGES  3200000
#define HIDDEN   64
#define N_GRAPHS 4096
#define IN_CH    2
#define N_CLASSES 7

// ---------------- degree / norm ----------------
__global__ void k_deg(const int* __restrict__ dst, float* __restrict__ deg) {
    int e = blockIdx.x * blockDim.x + threadIdx.x;
    if (e < N_EDGES) atomicAdd(&deg[dst[e]], 1.0f);
}

__global__ void k_dinv(float* __restrict__ deg) {
    int n = blockIdx.x * blockDim.x + threadIdx.x;
    if (n < N_NODES) {
        // +1 for self loop; deg >= 1 always -> dinv = rsqrt(deg)
        deg[n] = rsqrtf(deg[n] + 1.0f);
    }
}

// ---------------- layer 1 matmul (IN_CH=2) ----------------
__global__ void k_mm1(const float* __restrict__ x, const float* __restrict__ W1,
                      float* __restrict__ B) {
    int idx = blockIdx.x * blockDim.x + threadIdx.x;
    if (idx >= N_NODES * HIDDEN) return;
    int n = idx >> 6, c = idx & 63;
    B[idx] = x[n * 2 + 0] * W1[c] + x[n * 2 + 1] * W1[64 + c];
}

// ---------------- 64x64 matmul (layers 2,3) ----------------
__global__ void k_mm64(const float* __restrict__ A, const float* __restrict__ W,
                       float* __restrict__ B) {
    __shared__ float Ws[64 * 64];
    __shared__ float As[4 * 64];
    for (int i = threadIdx.x; i < 64 * 64; i += 256) Ws[i] = W[i];
    int lc = threadIdx.x & 63, ln = threadIdx.x >> 6;
    int n = blockIdx.x * 4 + ln;
    As[threadIdx.x] = (n < N_NODES) ? A[n * 64 + lc] : 0.0f;
    __syncthreads();
    float s = 0.0f;
#pragma unroll
    for (int k = 0; k < 64; ++k) s += As[ln * 64 + k] * Ws[k * 64 + lc];
    if (n < N_NODES) B[n * 64 + lc] = s;
}

// ---------------- self-loop init: A = dinv^2 * B ----------------
__global__ void k_selfinit(const float* __restrict__ B, const float* __restrict__ dinv,
                           float* __restrict__ A) {
    int i = blockIdx.x * blockDim.x + threadIdx.x;
    if (i < N_NODES * HIDDEN) {
        float d = dinv[i >> 6];
        A[i] = d * d * B[i];
    }
}

// ---------------- edge aggregation: A[dst] += norm * B[src] ----------------
__global__ void k_edge(const int* __restrict__ src, const int* __restrict__ dst,
                       const float* __restrict__ dinv, const float4* __restrict__ B4,
                       float* __restrict__ A) {
    int t = blockIdx.x * blockDim.x + threadIdx.x;
    int e = t >> 4;       // 16 threads per edge, 4 channels each
    int q = t & 15;
    if (e >= N_EDGES) return;
    int s = src[e], d = dst[e];
    float w = dinv[s] * dinv[d];
    float4 v = B4[s * 16 + q];
    float* out = &A[d * 64 + q * 4];
    atomicAdd(out + 0, w * v.x);
    atomicAdd(out + 1, w * v.y);
    atomicAdd(out + 2, w * v.z);
    atomicAdd(out + 3, w * v.w);
}

// ---------------- bias + relu in place ----------------
__global__ void k_biasrelu(float* __restrict__ A, const float* __restrict__ b) {
    int i = blockIdx.x * blockDim.x + threadIdx.x;
    if (i < N_NODES * HIDDEN) {
        float v = A[i] + b[i & 63];
        A[i] = v > 0.0f ? v : 0.0f;
    }
}

// ---------------- mean pool accumulation ----------------
__global__ void k_pool(const float* __restrict__ A, const int* __restrict__ batch,
                       float* __restrict__ sums, float* __restrict__ counts) {
    int idx = blockIdx.x * blockDim.x + threadIdx.x;
    if (idx >= N_NODES * HIDDEN) return;
    int n = idx >> 6, c = idx & 63;
    int g = batch[n];
    atomicAdd(&sums[g * 64 + c], A[idx]);
    if (c == 0) atomicAdd(&counts[g], 1.0f);
}

// ---------------- MLP head: one block (64 threads) per graph ----------------
__global__ void k_head(const float* __restrict__ sums, const float* __restrict__ counts,
                       const float* __restrict__ Wf1, const float* __restrict__ bf1,
                       const float* __restrict__ Wf2, const float* __restrict__ bf2,
                       float* __restrict__ out) {
    __shared__ float p[64];
    __shared__ float h[64];
    int g = blockIdx.x;
    int c = threadIdx.x;
    float cnt = counts[g];
    cnt = cnt > 1.0f ? cnt : 1.0f;
    p[c] = sums[g * 64 + c] / cnt;
    __syncthreads();
    float s = bf1[c];
#pragma unroll
    for (int k = 0; k < 64; ++k) s += p[k] * Wf1[k * 64 + c];
    h[c] = s > 0.0f ? s : 0.0f;
    __syncthreads();
    if (c < N_CLASSES) {
        float o = bf2[c];
#pragma unroll
        for (int k = 0; k < 64; ++k) o += h[k] * Wf2[k * N_CLASSES + c];
        out[g * N_CLASSES + c] = o;
    }
}

extern "C" void kernel_launch(void* const* d_in, const int* in_sizes, int n_in,
                              void* d_out, int out_size, void* d_ws, size_t ws_size,
                              hipStream_t stream) {
    const float* x   = (const float*)d_in[0];
    const int*   ei  = (const int*)d_in[1];   // [2, N_EDGES] -> row0 src, row1 dst
    const int*   bat = (const int*)d_in[2];
    const float* W1  = (const float*)d_in[3];
    const float* b1  = (const float*)d_in[4];
    const float* W2  = (const float*)d_in[5];
    const float* b2  = (const float*)d_in[6];
    const float* W3  = (const float*)d_in[7];
    const float* b3  = (const float*)d_in[8];
    const float* Wf1 = (const float*)d_in[9];
    const float* bf1 = (const float*)d_in[10];
    const float* Wf2 = (const float*)d_in[11];
    const float* bf2 = (const float*)d_in[12];
    float* out = (float*)d_out;

    const int* src = ei;
    const int* dst = ei + N_EDGES;

    float* ws    = (float*)d_ws;
    float* A     = ws;                          // N*64
    float* B     = A + (size_t)N_NODES * 64;    // N*64
    float* dinv  = B + (size_t)N_NODES * 64;    // N  (holds deg first, then dinv)
    float* sums  = dinv + N_NODES;              // 4096*64
    float* cnts  = sums + (size_t)N_GRAPHS * 64; // 4096

    // zero degree + pool accumulators (ws is poisoned each call)
    hipMemsetAsync(dinv, 0, (size_t)N_NODES * sizeof(float), stream);
    hipMemsetAsync(sums, 0, (size_t)(N_GRAPHS * 64 + N_GRAPHS) * sizeof(float), stream);

    const int BT = 256;
    int gEdges = (N_EDGES + BT - 1) / BT;
    int gNodes = (N_NODES + BT - 1) / BT;
    int gNH    = (N_NODES * HIDDEN + BT - 1) / BT;
    int gEdge16 = (N_EDGES * 16 + BT - 1) / BT;
    int gMM    = (N_NODES + 3) / 4;

    k_deg<<<gEdges, BT, 0, stream>>>(dst, dinv);
    k_dinv<<<gNodes, BT, 0, stream>>>(dinv);

    // ----- layer 1 -----
    k_mm1<<<gNH, BT, 0, stream>>>(x, W1, B);
    k_selfinit<<<gNH, BT, 0, stream>>>(B, dinv, A);
    k_edge<<<gEdge16, BT, 0, stream>>>(src, dst, dinv, (const float4*)B, A);
    k_biasrelu<<<gNH, BT, 0, stream>>>(A, b1);

    // ----- layer 2 -----
    k_mm64<<<gMM, BT, 0, stream>>>(A, W2, B);
    k_selfinit<<<gNH, BT, 0, stream>>>(B, dinv, A);
    k_edge<<<gEdge16, BT, 0, stream>>>(src, dst, dinv, (const float4*)B, A);
    k_biasrelu<<<gNH, BT, 0, stream>>>(A, b2);

    // ----- layer 3 -----
    k_mm64<<<gMM, BT, 0, stream>>>(A, W3, B);
    k_selfinit<<<gNH, BT, 0, stream>>>(B, dinv, A);
    k_edge<<<gEdge16, BT, 0, stream>>>(src, dst, dinv, (const float4*)B, A);
    k_biasrelu<<<gNH, BT, 0, stream>>>(A, b3);

    // ----- pool + head -----
    k_pool<<<gNH, BT, 0, stream>>>(A, bat, sums, cnts);
    k_head<<<N_GRAPHS, 64, 0, stream>>>(sums, cnts, Wf1, bf1, Wf2, bf2, out);
}

// Round 2
// 960.173 us; speedup vs baseline: 9.1713x; 9.1713x over previous
//
#include <hip/hip_runtime.h>

#define N_NODES  200000
#define N_EDGES  3200000
#define HIDDEN   64
#define N_GRAPHS 4096
#define N_CLASSES 7
#define SCAN_B   256
#define N_SCANB  ((N_NODES + SCAN_B - 1) / SCAN_B)   // 782

// ---------- degree histogram (int) ----------
__global__ void k_deg(const int* __restrict__ dst, int* __restrict__ deg) {
    int e = blockIdx.x * blockDim.x + threadIdx.x;
    if (e < N_EDGES) atomicAdd(&deg[dst[e]], 1);
}

// ---------- prefix scan pass 1: per-block exclusive scan ----------
__global__ void k_scan1(const int* __restrict__ deg, int* __restrict__ off,
                        int* __restrict__ bsum) {
    __shared__ int tmp[SCAN_B];
    int tid = threadIdx.x;
    int i = blockIdx.x * SCAN_B + tid;
    int v = (i < N_NODES) ? deg[i] : 0;
    int x = v;
    tmp[tid] = x;
    __syncthreads();
    for (int o = 1; o < SCAN_B; o <<= 1) {
        int y = (tid >= o) ? tmp[tid - o] : 0;
        __syncthreads();
        x += y;
        tmp[tid] = x;
        __syncthreads();
    }
    if (i < N_NODES) off[i] = x - v;          // exclusive within block
    if (tid == SCAN_B - 1) bsum[blockIdx.x] = x;  // block total
}

// ---------- prefix scan pass 2: serial scan of 782 block sums ----------
__global__ void k_scan2(int* __restrict__ bsum) {
    if (blockIdx.x == 0 && threadIdx.x == 0) {
        int run = 0;
        for (int i = 0; i < N_SCANB; ++i) { int t = bsum[i]; bsum[i] = run; run += t; }
    }
}

// ---------- finalize: add block base, init cursor, compute dinv ----------
__global__ void k_fin(const int* __restrict__ deg, int* __restrict__ off,
                      const int* __restrict__ bsum, int* __restrict__ cursor,
                      float* __restrict__ dinv) {
    int i = blockIdx.x * blockDim.x + threadIdx.x;
    if (i >= N_NODES) return;
    int o = off[i] + bsum[i >> 8];
    off[i] = o;
    cursor[i] = o;
    dinv[i] = rsqrtf((float)deg[i] + 1.0f);   // +1 self loop
}

// ---------- scatter edges into CSR buckets, precompute weight ----------
__global__ void k_scatter(const int* __restrict__ src, const int* __restrict__ dst,
                          const float* __restrict__ dinv, int* __restrict__ cursor,
                          int2* __restrict__ edges) {
    int e = blockIdx.x * blockDim.x + threadIdx.x;
    if (e >= N_EDGES) return;
    int s = src[e], d = dst[e];
    int pos = atomicAdd(&cursor[d], 1);
    float w = dinv[s] * dinv[d];
    edges[pos] = make_int2(s, __float_as_int(w));
}

// ---------- layer-1 pre-aggregation on raw 2-ch x ----------
__global__ void k_gather2(const int2* __restrict__ edges, const int* __restrict__ off,
                          const int* __restrict__ endv, const float* __restrict__ dinv,
                          const float2* __restrict__ x2, float2* __restrict__ g2) {
    int n = blockIdx.x * blockDim.x + threadIdx.x;
    if (n >= N_NODES) return;
    float dn = dinv[n];
    float2 xv = x2[n];
    float w0 = dn * dn;
    float ax = w0 * xv.x, ay = w0 * xv.y;
    int e1 = endv[n];
    for (int j = off[n]; j < e1; ++j) {
        int2 ed = edges[j];
        float w = __int_as_float(ed.y);
        float2 v = x2[ed.x];
        ax += w * v.x; ay += w * v.y;
    }
    g2[n] = make_float2(ax, ay);
}

// ---------- layer-1 pointwise: h1 = relu(g2 @ W1 + b1) ----------
__global__ void k_mm1f(const float2* __restrict__ g2, const float* __restrict__ W1,
                       const float* __restrict__ b1, float* __restrict__ A) {
    int idx = blockIdx.x * blockDim.x + threadIdx.x;
    if (idx >= N_NODES * HIDDEN) return;
    int n = idx >> 6, c = idx & 63;
    float2 g = g2[n];
    float v = g.x * W1[c] + g.y * W1[64 + c] + b1[c];
    A[idx] = v > 0.0f ? v : 0.0f;
}

// ---------- dense 64x64 matmul: B = A @ W ----------
__global__ void k_mm64(const float* __restrict__ A, const float* __restrict__ W,
                       float* __restrict__ B) {
    __shared__ float Ws[64 * 64];
    __shared__ float As[4 * 64];
    for (int i = threadIdx.x; i < 64 * 64; i += 256) Ws[i] = W[i];
    int lc = threadIdx.x & 63, ln = threadIdx.x >> 6;
    int n = blockIdx.x * 4 + ln;
    As[threadIdx.x] = A[n * 64 + lc];
    __syncthreads();
    float s = 0.0f;
#pragma unroll
    for (int k = 0; k < 64; ++k) s += As[ln * 64 + k] * Ws[k * 64 + lc];
    B[n * 64 + lc] = s;
}

// ---------- gather-aggregate 64ch + self loop + bias + relu ----------
// one wave per node; lane = sub(2b) x quad(4b); 4 edges in flight per iter
__global__ void k_gather64(const int2* __restrict__ edges, const int* __restrict__ off,
                           const int* __restrict__ endv, const float* __restrict__ dinv,
                           const float4* __restrict__ B4, const float* __restrict__ bias,
                           float4* __restrict__ A4) {
    int n = blockIdx.x * 4 + (threadIdx.x >> 6);
    int lane = threadIdx.x & 63;
    int sub = lane >> 4, q = lane & 15;
    float ax = 0.0f, ay = 0.0f, az = 0.0f, aw = 0.0f;
    if (sub == 0) {
        float d = dinv[n];
        float w = d * d;
        float4 v = B4[n * 16 + q];
        ax = w * v.x; ay = w * v.y; az = w * v.z; aw = w * v.w;
    }
    int e1 = endv[n];
    for (int j = off[n] + sub; j < e1; j += 4) {
        int2 ed = edges[j];
        float w = __int_as_float(ed.y);
        float4 v = B4[ed.x * 16 + q];
        ax += w * v.x; ay += w * v.y; az += w * v.z; aw += w * v.w;
    }
    // reduce across the 4 sub-slots (lane bits 4,5)
    ax += __shfl_xor(ax, 16, 64); ax += __shfl_xor(ax, 32, 64);
    ay += __shfl_xor(ay, 16, 64); ay += __shfl_xor(ay, 32, 64);
    az += __shfl_xor(az, 16, 64); az += __shfl_xor(az, 32, 64);
    aw += __shfl_xor(aw, 16, 64); aw += __shfl_xor(aw, 32, 64);
    if (sub == 0) {
        const float* b = bias + q * 4;
        float4 r;
        r.x = ax + b[0]; r.y = ay + b[1]; r.z = az + b[2]; r.w = aw + b[3];
        r.x = r.x > 0.0f ? r.x : 0.0f;
        r.y = r.y > 0.0f ? r.y : 0.0f;
        r.z = r.z > 0.0f ? r.z : 0.0f;
        r.w = r.w > 0.0f ? r.w : 0.0f;
        A4[n * 16 + q] = r;
    }
}

// ---------- segmented mean-pool accumulation (batch is sorted) ----------
#define PCHUNK 64
__global__ void k_pool(const float* __restrict__ A, const int* __restrict__ batch,
                       float* __restrict__ sums, float* __restrict__ cnts) {
    int c = threadIdx.x;            // 64 threads = 64 channels
    int n0 = blockIdx.x * PCHUNK;
    int n1 = n0 + PCHUNK; if (n1 > N_NODES) n1 = N_NODES;
    int gcur = batch[n0];
    float acc = 0.0f;
    int cnt = 0;
    for (int n = n0; n < n1; ++n) {
        int g = batch[n];
        if (g != gcur) {
            atomicAdd(&sums[gcur * 64 + c], acc);
            if (c == 0) atomicAdd(&cnts[gcur], (float)cnt);
            acc = 0.0f; cnt = 0; gcur = g;
        }
        acc += A[n * 64 + c];
        ++cnt;
    }
    atomicAdd(&sums[gcur * 64 + c], acc);
    if (c == 0) atomicAdd(&cnts[gcur], (float)cnt);
}

// ---------- MLP head ----------
__global__ void k_head(const float* __restrict__ sums, const float* __restrict__ cnts,
                       const float* __restrict__ Wf1, const float* __restrict__ bf1,
                       const float* __restrict__ Wf2, const float* __restrict__ bf2,
                       float* __restrict__ out) {
    __shared__ float p[64];
    __shared__ float h[64];
    int g = blockIdx.x;
    int c = threadIdx.x;
    float cnt = cnts[g];
    cnt = cnt > 1.0f ? cnt : 1.0f;
    p[c] = sums[g * 64 + c] / cnt;
    __syncthreads();
    float s = bf1[c];
#pragma unroll
    for (int k = 0; k < 64; ++k) s += p[k] * Wf1[k * 64 + c];
    h[c] = s > 0.0f ? s : 0.0f;
    __syncthreads();
    if (c < N_CLASSES) {
        float o = bf2[c];
#pragma unroll
        for (int k = 0; k < 64; ++k) o += h[k] * Wf2[k * N_CLASSES + c];
        out[g * N_CLASSES + c] = o;
    }
}

extern "C" void kernel_launch(void* const* d_in, const int* in_sizes, int n_in,
                              void* d_out, int out_size, void* d_ws, size_t ws_size,
                              hipStream_t stream) {
    const float* x   = (const float*)d_in[0];
    const int*   ei  = (const int*)d_in[1];
    const int*   bat = (const int*)d_in[2];
    const float* W1  = (const float*)d_in[3];
    const float* b1  = (const float*)d_in[4];
    const float* W2  = (const float*)d_in[5];
    const float* b2  = (const float*)d_in[6];
    const float* W3  = (const float*)d_in[7];
    const float* b3  = (const float*)d_in[8];
    const float* Wf1 = (const float*)d_in[9];
    const float* bf1 = (const float*)d_in[10];
    const float* Wf2 = (const float*)d_in[11];
    const float* bf2 = (const float*)d_in[12];
    float* out = (float*)d_out;

    const int* src = ei;
    const int* dst = ei + N_EDGES;

    char* p = (char*)d_ws;
    float* A    = (float*)p;                    p += (size_t)N_NODES * 64 * 4;
    float* B    = (float*)p;                    p += (size_t)N_NODES * 64 * 4;
    int2*  edges= (int2*)p;                     p += (size_t)N_EDGES * 8;
    int*   deg  = (int*)p;                      p += (size_t)N_NODES * 4;
    int*   off  = (int*)p;                      p += (size_t)N_NODES * 4;
    int*   cur  = (int*)p;                      p += (size_t)N_NODES * 4;
    float* dinv = (float*)p;                    p += (size_t)N_NODES * 4;
    float* g2   = (float*)p;                    p += (size_t)N_NODES * 2 * 4;
    int*   bsum = (int*)p;                      p += (size_t)1024 * 4;
    float* sums = (float*)p;                    p += (size_t)N_GRAPHS * 64 * 4;
    float* cnts = (float*)p;                    p += (size_t)N_GRAPHS * 4;

    hipMemsetAsync(deg, 0, (size_t)N_NODES * 4, stream);
    hipMemsetAsync(sums, 0, (size_t)(N_GRAPHS * 64 + N_GRAPHS) * 4, stream);

    const int BT = 256;
    int gEdges = (N_EDGES + BT - 1) / BT;
    int gNodes = (N_NODES + BT - 1) / BT;
    int gNH    = (N_NODES * HIDDEN + BT - 1) / BT;
    int gWave  = N_NODES / 4;                   // 50000, exact

    // ---- CSR build ----
    k_deg<<<gEdges, BT, 0, stream>>>(dst, deg);
    k_scan1<<<N_SCANB, SCAN_B, 0, stream>>>(deg, off, bsum);
    k_scan2<<<1, 64, 0, stream>>>(bsum);
    k_fin<<<gNodes, BT, 0, stream>>>(deg, off, bsum, cur, dinv);
    k_scatter<<<gEdges, BT, 0, stream>>>(src, dst, dinv, cur, edges);

    // ---- layer 1: aggregate raw x (2ch), then W1+bias+relu ----
    k_gather2<<<gNodes, BT, 0, stream>>>(edges, off, cur, dinv, (const float2*)x, (float2*)g2);
    k_mm1f<<<gNH, BT, 0, stream>>>((const float2*)g2, W1, b1, A);

    // ---- layer 2 ----
    k_mm64<<<gWave, BT, 0, stream>>>(A, W2, B);
    k_gather64<<<gWave, BT, 0, stream>>>(edges, off, cur, dinv, (const float4*)B, b2, (float4*)A);

    // ---- layer 3 ----
    k_mm64<<<gWave, BT, 0, stream>>>(A, W3, B);
    k_gather64<<<gWave, BT, 0, stream>>>(edges, off, cur, dinv, (const float4*)B, b3, (float4*)A);

    // ---- pool + head ----
    k_pool<<<(N_NODES + PCHUNK - 1) / PCHUNK, 64, 0, stream>>>(A, bat, sums, cnts);
    k_head<<<N_GRAPHS, 64, 0, stream>>>(sums, cnts, Wf1, bf1, Wf2, bf2, out);
}